// Round 12
// baseline (488.511 us; speedup 1.0000x reference)
//
#include <hip/hip_runtime.h>
#include <math.h>

// Problem constants (from reference):
constexpr int Bc = 4, Tc = 512, Cc = 768, Hc = 12, HSc = 64;
constexpr int QKVN = 3 * Cc;  // 2304
constexpr double EPSd = 1e-6;

typedef __attribute__((ext_vector_type(8))) short short8;
typedef __attribute__((ext_vector_type(4))) float f32x4;

// f32 <-> bf16 (RNE), header-independent
__device__ __forceinline__ unsigned short f2bf(float f) {
  unsigned u = __float_as_uint(f);
  u += 0x7fffu + ((u >> 16) & 1u);
  return (unsigned short)(u >> 16);
}
__device__ __forceinline__ float bf2f(unsigned short h) {
  return __uint_as_float((unsigned)h << 16);
}

// ---------------------------------------------------------------------------
// prep_rows<C>: split fp32 row-major matrix into C bf16 components
// (h = bf16(x), m = bf16(x-h), ...). out layout [C][elems].
// ---------------------------------------------------------------------------
template <int C>
__global__ void __launch_bounds__(256) prep_rows(
    const float* __restrict__ X, unsigned short* __restrict__ out, int elems) {
  const int idx = blockIdx.x * 256 + threadIdx.x;
  const float4 v = ((const float4*)X)[idx];
  float rem[4] = {v.x, v.y, v.z, v.w};
#pragma unroll
  for (int cc = 0; cc < C; ++cc) {
    ushort4 h;
    h.x = f2bf(rem[0]); rem[0] -= bf2f(h.x);
    h.y = f2bf(rem[1]); rem[1] -= bf2f(h.y);
    h.z = f2bf(rem[2]); rem[2] -= bf2f(h.z);
    h.w = f2bf(rem[3]); rem[3] -= bf2f(h.w);
    ((ushort4*)(out + (size_t)cc * elems))[idx] = h;
  }
}

// ---------------------------------------------------------------------------
// prep_wt<C>: W [K][N] fp32 -> out[C][N][K] bf16 components (transposed so
// the GEMM's B operand is [n][k] = the verified m97 gemm_bt B^T layout).
// ---------------------------------------------------------------------------
template <int C>
__global__ void __launch_bounds__(256) prep_wt(
    const float* __restrict__ W, unsigned short* __restrict__ out,
    int K, int N) {
  __shared__ float tile[64][65];
  const int n0 = blockIdx.x * 64, k0 = blockIdx.y * 64;
  const int c = threadIdx.x & 63, r4 = threadIdx.x >> 6;
  for (int r = r4; r < 64; r += 4)
    tile[r][c] = W[(size_t)(k0 + r) * N + n0 + c];
  __syncthreads();
  for (int r = r4; r < 64; r += 4) {
    float rem = tile[c][r];  // = W[k0+c][n0+r]
#pragma unroll
    for (int cc = 0; cc < C; ++cc) {
      const unsigned short h = f2bf(rem);
      out[((size_t)cc * N + n0 + r) * K + k0 + c] = h;
      rem -= bf2f(h);
    }
  }
}

// ---------------------------------------------------------------------------
// MFMA GEMM via bf16 split: out[M,N] = sum_{ci+cj<=MAXORD} Ac[ci] @ Bt[cj]^T
// + bias. Ac: [C][M][K] bf16, Bt: [C][N][K] bf16 (B^T layout). Block 64x64,
// 4 waves in 2x2, wave tile 32x32 = 2x2 mfma_f32_16x16x32_bf16 tiles.
// A/B fragments: lane m(or n)=lane&15, k=quad*8+j (m97-verified gemm_bt
// pattern); C/D: col=lane&15, row=quad*4+reg (m89-verified).
// qkv uses C=3/MAXORD=2 (6 terms): dropped terms <=2^-26 rel -> fp32-class
// accuracy, same decision-perturbation class proven flip-free since R4.
// proj uses C=2/MAXORD=1 (3 terms): ~2^-18 rel, output-only path.
// LDS stride 40 shorts: fragment b128 reads 2-way aliased (free).
// ---------------------------------------------------------------------------
template <int C, int MAXORD>
__global__ void __launch_bounds__(256) gemm_mfma(
    const unsigned short* __restrict__ Ac, const unsigned short* __restrict__ Bt,
    const float* __restrict__ bias, float* __restrict__ outp,
    int N, int K, int M) {
  constexpr int BK = 32;
  __shared__ unsigned short Ash[C][64][40];
  __shared__ unsigned short Bsh[C][64][40];
  const int tid = threadIdx.x;
  const int lane = tid & 63, wid = tid >> 6;
  const int wm = wid >> 1, wn = wid & 1;
  const int rb = blockIdx.x * 64, cb = blockIdx.y * 64;
  const int l15 = lane & 15, q = lane >> 4;
  const int srow = tid >> 2, skoff = (tid & 3) * 8;

  const unsigned short* aP[C];
  const unsigned short* bP[C];
#pragma unroll
  for (int cc = 0; cc < C; ++cc) {
    aP[cc] = Ac + ((size_t)cc * M + rb + srow) * K + skoff;
    bP[cc] = Bt + ((size_t)cc * N + cb + srow) * K + skoff;
  }
  f32x4 acc[2][2];
#pragma unroll
  for (int mt = 0; mt < 2; ++mt)
#pragma unroll
    for (int nt = 0; nt < 2; ++nt) acc[mt][nt] = (f32x4){0.f, 0.f, 0.f, 0.f};

  uint4 pa[C], pb[C];
#pragma unroll
  for (int cc = 0; cc < C; ++cc) {
    pa[cc] = *(const uint4*)aP[cc];
    pb[cc] = *(const uint4*)bP[cc];
  }
  const int nIter = K / BK;
  for (int it = 0; it < nIter; ++it) {
    __syncthreads();
#pragma unroll
    for (int cc = 0; cc < C; ++cc) {
      *(uint4*)&Ash[cc][srow][skoff] = pa[cc];
      *(uint4*)&Bsh[cc][srow][skoff] = pb[cc];
    }
    __syncthreads();
    if (it + 1 < nIter) {
#pragma unroll
      for (int cc = 0; cc < C; ++cc) {
        aP[cc] += BK;
        bP[cc] += BK;
        pa[cc] = *(const uint4*)aP[cc];
        pb[cc] = *(const uint4*)bP[cc];
      }
    }
    short8 af[C][2], bf[C][2];
#pragma unroll
    for (int cc = 0; cc < C; ++cc)
#pragma unroll
      for (int t = 0; t < 2; ++t) {
        af[cc][t] = *(const short8*)&Ash[cc][wm * 32 + t * 16 + l15][q * 8];
        bf[cc][t] = *(const short8*)&Bsh[cc][wn * 32 + t * 16 + l15][q * 8];
      }
#pragma unroll
    for (int mt = 0; mt < 2; ++mt)
#pragma unroll
      for (int nt = 0; nt < 2; ++nt)
#pragma unroll
        for (int ci = 0; ci < C; ++ci)
#pragma unroll
          for (int cj = 0; cj < C; ++cj)
            if (ci + cj <= MAXORD)
              acc[mt][nt] = __builtin_amdgcn_mfma_f32_16x16x32_bf16(
                  af[ci][mt], bf[cj][nt], acc[mt][nt], 0, 0, 0);
  }
#pragma unroll
  for (int mt = 0; mt < 2; ++mt)
#pragma unroll
    for (int nt = 0; nt < 2; ++nt) {
      const int col = cb + wn * 32 + nt * 16 + l15;
      const float bcol = bias[col];
#pragma unroll
      for (int rr = 0; rr < 4; ++rr) {
        const int row = rb + wm * 32 + mt * 16 + q * 4 + rr;
        outp[(size_t)row * N + col] = acc[mt][nt][rr] + bcol;
      }
    }
}

// ---------------------------------------------------------------------------
// S[bh][i][j] = q_i . k_j (fp32). LOWER-TRIANGLE TILES ONLY; j>i masked in
// the fused topk. 64x64x64 tile, 4x4 register tile, operands [d][tok] in LDS.
// ---------------------------------------------------------------------------
__global__ void __launch_bounds__(256) sims_kernel(
    const float* __restrict__ qkv, float* __restrict__ S) {
  const int bh = blockIdx.y;
  const int b = bh / Hc, h = bh % Hc;
  int it = 0;
  {
    const int t = blockIdx.x;
    while ((it + 1) * (it + 2) / 2 <= t) ++it;
  }
  const int jt = blockIdx.x - it * (it + 1) / 2;
  const int tid = threadIdx.x;
  const int tx = tid & 15, ty = tid >> 4;
  __shared__ float Qs[HSc][68];
  __shared__ float Ks[HSc][68];
  const float* base = qkv + (size_t)b * Tc * QKVN + h * HSc;
  {
    const int row = tid >> 2;
    const int d0 = (tid & 3) * 16;
    const float* qrow = base + (size_t)(it * 64 + row) * QKVN;
    const float* krow = base + (size_t)(jt * 64 + row) * QKVN + Cc;
#pragma unroll
    for (int u = 0; u < 4; ++u) {
      const float4 q4 = *(const float4*)&qrow[d0 + u * 4];
      const float4 k4 = *(const float4*)&krow[d0 + u * 4];
      Qs[d0 + u * 4 + 0][row] = q4.x; Qs[d0 + u * 4 + 1][row] = q4.y;
      Qs[d0 + u * 4 + 2][row] = q4.z; Qs[d0 + u * 4 + 3][row] = q4.w;
      Ks[d0 + u * 4 + 0][row] = k4.x; Ks[d0 + u * 4 + 1][row] = k4.y;
      Ks[d0 + u * 4 + 2][row] = k4.z; Ks[d0 + u * 4 + 3][row] = k4.w;
    }
  }
  __syncthreads();
  float acc[4][4];
#pragma unroll
  for (int m = 0; m < 4; ++m)
#pragma unroll
    for (int n = 0; n < 4; ++n) acc[m][n] = 0.0f;
#pragma unroll 4
  for (int d = 0; d < HSc; ++d) {
    const float4 a4 = *(const float4*)&Qs[d][ty * 4];
    const float4 b4 = *(const float4*)&Ks[d][tx * 4];
    const float a[4] = {a4.x, a4.y, a4.z, a4.w};
    const float bv[4] = {b4.x, b4.y, b4.z, b4.w};
#pragma unroll
    for (int m = 0; m < 4; ++m)
#pragma unroll
      for (int n = 0; n < 4; ++n) acc[m][n] += a[m] * bv[n];
  }
  float* Shead = S + (size_t)bh * Tc * Tc;
#pragma unroll
  for (int m = 0; m < 4; ++m) {
    const int i = it * 64 + ty * 4 + m;
    float4 o4 = {acc[m][0], acc[m][1], acc[m][2], acc[m][3]};
    *(float4*)&Shead[(size_t)i * Tc + jt * 64 + tx * 4] = o4;
  }
}

// ---------------------------------------------------------------------------
// FUSED top-16 + greedy DPP selection (byte-identical to passing R11).
// ---------------------------------------------------------------------------
__global__ void __launch_bounds__(256, 4) topk_select_kernel(
    const float* __restrict__ qkv, const float* __restrict__ S,
    float* __restrict__ y) {
  const int tid = threadIdx.x;
  const int wv = tid >> 6, lane = tid & 63;
  const int tok = blockIdx.x * 4 + wv;  // bh*512 + i
  const int bh = tok >> 9;
  const int i = tok & (Tc - 1);
  const int b = bh / Hc;
  const int h = bh % Hc;
  const int m = lane >> 2;   // candidate 0..15
  const int q = lane & 3;    // quarter 0..3 (16 dims each)

  const float* base = qkv + (size_t)b * Tc * QKVN + h * HSc;
  const float* kbase = base + Cc;
  const float* vbase = base + 2 * Cc;

  __shared__ int selS[4][8];

  // ---- phase 1: top-16 scan over the precomputed S row ----
  const float4* Sq = reinterpret_cast<const float4*>(S + (size_t)tok * Tc);
  unsigned long long key[8];
#pragma unroll
  for (int r = 0; r < 2; ++r) {
    const float4 v4 = Sq[lane * 2 + r];
    const float vv[4] = {v4.x, v4.y, v4.z, v4.w};
#pragma unroll
    for (int c = 0; c < 4; ++c) {
      const int j = lane * 8 + r * 4 + c;
      const unsigned u = __float_as_uint(vv[c]);
      const unsigned s = (u & 0x80000000u) ? ~u : (u | 0x80000000u);
      key[r * 4 + c] = (j <= i)
          ? (((unsigned long long)s << 32) | (unsigned)(511 - j))
          : 0ull;
    }
  }
  unsigned avail = 0;
  int tidx = 0;  // candidate m's token index, kept by its 4-lane cluster
  for (int mm = 0; mm < 16; ++mm) {
    unsigned long long bk = 0;
#pragma unroll
    for (int r = 0; r < 8; ++r) bk = (key[r] > bk) ? key[r] : bk;
#pragma unroll
    for (int msk = 1; msk <= 32; msk <<= 1) {
      const unsigned long long ok = __shfl_xor(bk, msk);
      bk = (ok > bk) ? ok : bk;
    }
    const int j = (511 - (int)(unsigned)(bk & 0xFFFFFFFFull)) & 511;
    const unsigned shi = (unsigned)(bk >> 32);
    if (m == mm) tidx = j;
    if (shi > 0x007FFFFFu && j != i) avail |= (1u << mm);
#pragma unroll
    for (int r = 0; r < 8; ++r) key[r] = (key[r] == bk) ? 0ull : key[r];
  }

  // ---- phase 2: greedy DPP (incremental Cholesky, proven R4-R11) ----
  float kreg[16], kireg[16];
  {
    const float* kc = kbase + (size_t)tidx * QKVN + q * 16;
    const float* ki = kbase + (size_t)i * QKVN + q * 16;
#pragma unroll
    for (int u = 0; u < 4; ++u) {
      const float4 c4 = *(const float4*)&kc[u * 4];
      const float4 i4 = *(const float4*)&ki[u * 4];
      kreg[u * 4 + 0] = c4.x; kreg[u * 4 + 1] = c4.y;
      kreg[u * 4 + 2] = c4.z; kreg[u * 4 + 3] = c4.w;
      kireg[u * 4 + 0] = i4.x; kireg[u * 4 + 1] = i4.y;
      kireg[u * 4 + 2] = i4.z; kireg[u * 4 + 3] = i4.w;
    }
  }
  float cnorm_f = 0.0f, c0_f = 0.0f, kii_f = 0.0f;
#pragma unroll
  for (int e = 0; e < 16; ++e) {
    cnorm_f += kreg[e] * kreg[e];
    c0_f += kreg[e] * kireg[e];
    kii_f += kireg[e] * kireg[e];
  }
  cnorm_f += __shfl_xor(cnorm_f, 1); cnorm_f += __shfl_xor(cnorm_f, 2);
  c0_f += __shfl_xor(c0_f, 1);       c0_f += __shfl_xor(c0_f, 2);
  kii_f += __shfl_xor(kii_f, 1);     kii_f += __shfl_xor(kii_f, 2);

  const double kii = (double)kii_f;
  double z[8];
#pragma unroll
  for (int t = 0; t < 8; ++t) z[t] = 0.0;
  z[0] = (double)c0_f / sqrt(kii);
  double schur = (double)cnorm_f - z[0] * z[0];
  double detS = kii;
  double cur_s = -log(kii + EPSd);
  int count = 1;
  if (lane == 0) selS[wv][0] = i;

#pragma unroll
  for (int it = 0; it < 7; ++it) {
    const double D = detS * schur + EPSd;
    const double sval = -log(D) / (double)(it + 2);
    const bool act = (avail >> m) & 1u;
    const double sorig = act ? sval : -INFINITY;
    double bkey = __builtin_isnan(sorig) ? INFINITY : sorig;
    int bm = m;
#pragma unroll
    for (int msk = 1; msk <= 32; msk <<= 1) {
      const double ok2 = __shfl_xor(bkey, msk);
      const int om = __shfl_xor(bm, msk);
      const bool t2 = (ok2 > bkey) || (ok2 == bkey && om < bm);
      bkey = t2 ? ok2 : bkey;
      bm = t2 ? om : bm;
    }
    const double best_s = __shfl(sorig, bm * 4);  // original (maybe NaN)
    const bool X = (avail != 0u) && ((best_s > cur_s) || (it == 0));
    if (!X) break;  // wave-uniform: first reject -> done forever
    float cp_f = 0.0f;
#pragma unroll
    for (int e = 0; e < 16; ++e) {
      const float kb = __shfl(kreg[e], bm * 4 + q);
      cp_f += kreg[e] * kb;
    }
    cp_f += __shfl_xor(cp_f, 1); cp_f += __shfl_xor(cp_f, 2);
    const double schur_b = __shfl(schur, bm * 4);
    double sum = 0.0;
#pragma unroll
    for (int t = 0; t <= it; ++t) {
      const double zbt = __shfl(z[t], bm * 4);
      sum += z[t] * zbt;
    }
    const double znew = ((double)cp_f - sum) / sqrt(schur_b);
    z[it + 1] = znew;
    schur -= znew * znew;
    detS *= schur_b;
    cur_s = best_s;
    avail &= ~(1u << bm);
    ++count;
    const int selIdx = __shfl(tidx, bm * 4);
    if (lane == 0) selS[wv][it + 1] = selIdx;
  }

  // output = mean of selected v rows; y is [B,T,H,HS]
  double acc = 0.0;
#pragma unroll
  for (int a = 0; a < 8; ++a)
    if (a < count) acc += (double)vbase[(size_t)selS[wv][a] * QKVN + lane];
  y[(((size_t)b * Tc + i) * Hc + h) * HSc + lane] =
      (float)(acc / (double)count);
}

// ---------------------------------------------------------------------------
extern "C" void kernel_launch(void* const* d_in, const int* in_sizes, int n_in,
                              void* d_out, int out_size, void* d_ws, size_t ws_size,
                              hipStream_t stream) {
  (void)in_sizes; (void)n_in; (void)out_size; (void)ws_size;
  const float* x  = (const float*)d_in[0];
  const float* Wa = (const float*)d_in[1];
  const float* ba = (const float*)d_in[2];
  const float* Wp = (const float*)d_in[3];
  const float* bp = (const float*)d_in[4];
  float* out = (float*)d_out;

  const int M = Bc * Tc;               // 2048
  const int elems = M * Cc;            // 1,572,864

  // Workspace (75.5 MB, same as R11):
  float* qkv = (float*)d_ws;                            // 18.87 MB
  float* y   = qkv + (size_t)M * QKVN;                  //  6.29 MB
  // Region B (50.33 MB), three aliased phases:
  //  A: Xc (3x bf16 X, 9.44 MB) + Wat (3x bf16 Wa^T, 10.62 MB) — dead after qkv gemm
  //  B: S (50.33 MB) — dead after topk_select
  //  C: Yc (2x bf16 y, 6.29 MB) + Wpt (2x bf16 Wp^T, 2.36 MB)
  float* regionB = y + (size_t)M * Cc;
  unsigned short* Xc  = (unsigned short*)regionB;
  unsigned short* Wat = Xc + (size_t)3 * elems;
  float* S = regionB;
  unsigned short* Yc  = (unsigned short*)regionB;
  unsigned short* Wpt = Yc + (size_t)2 * elems;

  // 1) split X, transpose+split Wa
  hipLaunchKernelGGL((prep_rows<3>), dim3(elems / 1024), dim3(256), 0,
                     stream, x, Xc, elems);
  hipLaunchKernelGGL((prep_wt<3>), dim3(QKVN / 64, Cc / 64), dim3(256), 0,
                     stream, Wa, Wat, Cc, QKVN);
  // 2) qkv = x @ W_attn + b_attn via 6-term bf16 MFMA (fp32-class accuracy)
  hipLaunchKernelGGL((gemm_mfma<3, 2>), dim3(M / 64, QKVN / 64), dim3(256), 0,
                     stream, Xc, Wat, ba, qkv, QKVN, Cc, M);
  // 3) S = Q K^T per head, lower-triangle tiles only
  hipLaunchKernelGGL(sims_kernel, dim3(36, Bc * Hc), dim3(256), 0,
                     stream, qkv, S);
  // 4) fused top-16 + greedy DPP (1 wave/token)
  hipLaunchKernelGGL(topk_select_kernel, dim3(Bc * Hc * Tc / 4), dim3(256), 0,
                     stream, qkv, S, y);
  // 5) split y, transpose+split Wp
  hipLaunchKernelGGL((prep_rows<2>), dim3(elems / 1024), dim3(256), 0,
                     stream, y, Yc, elems);
  hipLaunchKernelGGL((prep_wt<2>), dim3(Cc / 64, Cc / 64), dim3(256), 0,
                     stream, Wp, Wpt, Cc, Cc);
  // 6) out = y @ W_proj + b_proj via 3-term bf16 MFMA
  hipLaunchKernelGGL((gemm_mfma<2, 1>), dim3(M / 64, Cc / 64), dim3(256), 0,
                     stream, Yc, Wpt, bp, out, Cc, Cc, M);
}